// Round 1
// 5495.168 us; speedup vs baseline: 1.0075x; 1.0075x over previous
//
#include <hip/hip_runtime.h>
#include <hip/hip_bf16.h>
#include <math.h>

#define NB 32      // batch
#define NN 500     // nodes
#define NF 32      // channels

typedef float f32x4 __attribute__((ext_vector_type(4)));
typedef short bf16x8 __attribute__((ext_vector_type(8)));

__device__ __forceinline__ float sigf(float x) { return 1.0f / (1.0f + __expf(-x)); }

__device__ __forceinline__ unsigned short bf16rne(float x) {
  unsigned int u = __float_as_uint(x);
  unsigned int r = u + 0x7FFFu + ((u >> 16) & 1u);
  return (unsigned short)(r >> 16);
}
__device__ __forceinline__ float bfval(unsigned short h) {
  return __uint_as_float((unsigned int)h << 16);
}

// h[b,c,n,t] = b_start[c] + sum_ci w_start[c,ci]*padded_x[b,ci,n,t]; pad 7 zeros at front (19)
__global__ void k_start(const float* x, const float* w, const float* bias, float* h) {
  int idx = blockIdx.x * 256 + threadIdx.x;
  const int total = NB * NF * NN * 19;
  if (idx >= total) return;
  int t = idx % 19;
  int n = (idx / 19) % NN;
  int c = (idx / (19 * NN)) % NF;
  int b = idx / (19 * NN * NF);
  float v = bias[c];
  if (t >= 7) {
    int tx = t - 7;
    v += w[c * 2 + 0] * x[((size_t)(b * 2 + 0) * NN + n) * 12 + tx];
    v += w[c * 2 + 1] * x[((size_t)(b * 2 + 1) * NN + n) * 12 + tx];
  }
  h[idx] = v;
}

// skip0[b,c,n] = b_sk0[c] + sum_{ci,k>=7} w_sk0[c,ci,k]*x[b,ci,n,k-7]
__global__ void k_skip0(const float* x, const float* w, const float* bias, float* s0) {
  int idx = blockIdx.x * 256 + threadIdx.x;
  const int total = NB * 64 * NN;
  if (idx >= total) return;
  int n = idx % NN;
  int c = (idx / NN) % 64;
  int b = idx / (NN * 64);
  float v = bias[c];
  for (int ci = 0; ci < 2; ci++)
    for (int k = 7; k < 19; k++)
      v += w[(c * 2 + ci) * 19 + k] * x[((size_t)(b * 2 + ci) * NN + n) * 12 + (k - 7)];
  s0[idx] = v;
}

// ---- fused gated-TCN + fc; gtu_seg generalized over LDS strides (TS=time, CS=channel) ----
template<int K, int L, int TS, int CS, int TCAT, int TO>
__device__ __forceinline__ void gtu_seg(const float* __restrict__ wseg,
                                        const float* __restrict__ bg,
                                        const float* __restrict__ hbase,
                                        const float* __restrict__ fw,
                                        float (&oacc)[TO], int c, int tbase) {
  float y0[L], y1[L];
#pragma unroll
  for (int t = 0; t < L; t++) { y0[t] = 0.f; y1[t] = 0.f; }
#pragma unroll 2
  for (int ci = 0; ci < NF; ci++) {
    float hrow[L + K - 1];
#pragma unroll
    for (int t = 0; t < L + K - 1; t++) hrow[t] = hbase[ci * CS + t * TS];
    float w0[K], w1[K];
#pragma unroll
    for (int j = 0; j < K; j++) {
      w0[j] = wseg[(c * NF + ci) * K + j];
      w1[j] = wseg[((c + 32) * NF + ci) * K + j];
    }
#pragma unroll
    for (int t = 0; t < L; t++)
#pragma unroll
      for (int j = 0; j < K; j++) {
        y0[t] += w0[j] * hrow[t + j];
        y1[t] += w1[j] * hrow[t + j];
      }
  }
  float b0 = bg[c], b1 = bg[c + 32];
#pragma unroll
  for (int t = 0; t < L; t++) {
    float tcv = tanhf(y0[t] + b0) * sigf(y1[t] + b1);
#pragma unroll
    for (int o = 0; o < TO; o++) oacc[o] += tcv * fw[o * TCAT + tbase + t];
  }
}

// standard-layout input h[b,c,n,t]
template<int TI, int TO>
__global__ __launch_bounds__(256) void k_gtufc_t(
    const float* __restrict__ h,
    const float* __restrict__ wg3, const float* __restrict__ bg3,
    const float* __restrict__ wg5, const float* __restrict__ bg5,
    const float* __restrict__ wg7, const float* __restrict__ bg7,
    const float* __restrict__ fw, const float* __restrict__ fb,
    const float* __restrict__ res, float* __restrict__ out) {
  constexpr int TCAT = 3 * TI - 12;
  constexpr int TP = (TI + 3) & ~3;
  constexpr int OFF = TI - TO;
  const int b = blockIdx.y;
  const int n0 = blockIdx.x * 8;
  const int tid = threadIdx.x;
  const int c = tid & 31, nn = tid >> 5;
  const int n = n0 + nn;
  __shared__ float hs[8 * NF * TP];
  for (int l = tid; l < 8 * NF * TP; l += 256) {
    int t = l % TP;
    int ci = (l / TP) % NF;
    int n2 = l / (TP * NF);
    int gn = n0 + n2;
    hs[l] = (t < TI && gn < NN) ? h[((size_t)(b * NF + ci) * NN + gn) * TI + t] : 0.f;
  }
  __syncthreads();
  const float* hbase = hs + nn * NF * TP;
  float oacc[TO];
#pragma unroll
  for (int o = 0; o < TO; o++) oacc[o] = 0.f;
  gtu_seg<3, TI - 2, 1, TP, TCAT, TO>(wg3, bg3, hbase, fw, oacc, c, 0);
  gtu_seg<5, TI - 4, 1, TP, TCAT, TO>(wg5, bg5, hbase, fw, oacc, c, TI - 2);
  gtu_seg<7, TI - 6, 1, TP, TCAT, TO>(wg7, bg7, hbase, fw, oacc, c, 2 * TI - 6);
  if (n < NN) {
    size_t base = (size_t)(b * NF + c) * NN + n;
#pragma unroll
    for (int o = 0; o < TO; o++) {
      float v = fmaxf(hbase[c * TP + OFF + o] + oacc[o] + fb[o], 0.f);
      if (res) v += res[base * TI + OFF + o];
      out[base * TO + o] = v;
    }
  }
}

// t-major input hX[b][n][t*NF+f] (cheb output layout); output standard layout
template<int TI, int TO>
__global__ __launch_bounds__(256) void k_gtufc_x(
    const float* __restrict__ hX,
    const float* __restrict__ wg3, const float* __restrict__ bg3,
    const float* __restrict__ wg5, const float* __restrict__ bg5,
    const float* __restrict__ wg7, const float* __restrict__ bg7,
    const float* __restrict__ fw, const float* __restrict__ fb,
    const float* __restrict__ res, float* __restrict__ out) {
  constexpr int TCAT = 3 * TI - 12;
  constexpr int NFT = NF * TI;
  constexpr int OFF = TI - TO;
  const int b = blockIdx.y;
  const int n0 = blockIdx.x * 8;
  const int tid = threadIdx.x;
  const int c = tid & 31, nn = tid >> 5;
  const int n = n0 + nn;
  __shared__ float hs[8 * NFT];
  for (int l = tid; l < 8 * NFT; l += 256) {
    int n2 = l / NFT, l2 = l % NFT;
    int gn = n0 + n2;
    hs[l] = (gn < NN) ? hX[(size_t)(b * NN + gn) * NFT + l2] : 0.f;
  }
  __syncthreads();
  const float* hbase = hs + nn * NFT;
  float oacc[TO];
#pragma unroll
  for (int o = 0; o < TO; o++) oacc[o] = 0.f;
  gtu_seg<3, TI - 2, NF, 1, TCAT, TO>(wg3, bg3, hbase, fw, oacc, c, 0);
  gtu_seg<5, TI - 4, NF, 1, TCAT, TO>(wg5, bg5, hbase, fw, oacc, c, TI - 2);
  gtu_seg<7, TI - 6, NF, 1, TCAT, TO>(wg7, bg7, hbase, fw, oacc, c, 2 * TI - 6);
  if (n < NN) {
    size_t base = (size_t)(b * NF + c) * NN + n;
#pragma unroll
    for (int o = 0; o < TO; o++) {
      float v = fmaxf(hbase[(OFF + o) * NF + c] + oacc[o] + fb[o], 0.f);
      if (res) v += res[base * TI + OFF + o];
      out[base * TO + o] = v;
    }
  }
}

// ---- skip conv, LDS h staging, weights in registers, K unrolled ----
template<int TI, int K>
__global__ __launch_bounds__(256) void k_skipconv_t(
    const float* __restrict__ h, const float* __restrict__ w,
    const float* __restrict__ bias, const float* __restrict__ prev, int prevT,
    float* __restrict__ out) {
  constexpr int TP = (TI + 3) & ~3;
  const int b = blockIdx.y, n0 = blockIdx.x * 8, tid = threadIdx.x;
  __shared__ float hs[8 * NF * TP];
  for (int l = tid; l < 8 * NF * TP; l += 256) {
    int t = l % TP;
    int ci = (l / TP) % NF;
    int n2 = l / (TP * NF);
    int gn = n0 + n2;
    hs[l] = (t < TI && gn < NN) ? h[((size_t)(b * NF + ci) * NN + gn) * TI + t] : 0.f;
  }
  __syncthreads();
  const int c = tid & 63, ng = tid >> 6;
  float bv = bias[c];
  float o[2][7];
#pragma unroll
  for (int q = 0; q < 2; q++)
#pragma unroll
    for (int t = 0; t < 7; t++) o[q][t] = bv;
  for (int ci = 0; ci < NF; ci++) {
    float wv[K];
#pragma unroll
    for (int j = 0; j < K; j++) wv[j] = w[(c * NF + ci) * K + j];
#pragma unroll
    for (int q = 0; q < 2; q++) {
      const float* hp = hs + ((ng + q * 4) * NF + ci) * TP;
#pragma unroll
      for (int t = 0; t < 7; t++) {
        float s = 0.f;
#pragma unroll
        for (int j = 0; j < K; j++) s += wv[j] * hp[t + j];
        o[q][t] += s;
      }
    }
  }
#pragma unroll
  for (int q = 0; q < 2; q++) {
    int n = n0 + ng + q * 4;
    if (n < NN) {
      size_t base = (size_t)(b * 64 + c) * NN + n;
#pragma unroll
      for (int t = 0; t < 7; t++) {
        float pv = (prevT == 1) ? prev[base] : prev[base * 7 + t];
        out[base * 7 + t] = o[q][t] + pv;
      }
    }
  }
}

// ---- temporal attention ----
__global__ void k_ta_lhs1(const float* h, const float* u1, float* out, int T) {
  int total = NB * T * NF;
  int idx = blockIdx.x * 256 + threadIdx.x;
  if (idx >= total) return;
  int f = idx % NF;
  int t = (idx / NF) % T;
  int b = idx / (NF * T);
  const float* hp = h + ((size_t)(b * NF + f) * NN) * T + t;
  float acc = 0.f;
  for (int n = 0; n < NN; n++) acc += hp[(size_t)n * T] * u1[n];
  out[(b * T + t) * NF + f] = acc;
}
__global__ void k_ta_lhs(const float* l1, const float* u2, float* out, int T) {
  int total = NB * T * NN;
  int idx = blockIdx.x * 256 + threadIdx.x;
  if (idx >= total) return;
  int n = idx % NN;
  int t = (idx / NN) % T;
  int b = idx / (NN * T);
  float acc = 0.f;
  for (int f = 0; f < NF; f++) acc += l1[(b * T + t) * NF + f] * u2[f * NN + n];
  out[idx] = acc;  // (b,t,n)
}
__global__ void k_ta_rhs(const float* h, const float* u3, float* out, int T) {
  int total = NB * NN * T;
  int idx = blockIdx.x * 256 + threadIdx.x;
  if (idx >= total) return;
  int t = idx % T;
  int n = (idx / T) % NN;
  int b = idx / (T * NN);
  float acc = 0.f;
  for (int f = 0; f < NF; f++) acc += u3[f] * h[((size_t)(b * NF + f) * NN + n) * T + t];
  out[idx] = acc;  // (b,n,t)
}
// fused: e0 = sigf(lhs@rhs + be); e1 = ve@e0; e = softmax over t. one block per b.
__global__ __launch_bounds__(256) void k_ta_att(const float* __restrict__ lhs,
                                                const float* __restrict__ rhs,
                                                const float* __restrict__ be,
                                                const float* __restrict__ ve,
                                                float* __restrict__ e, int T) {
  int b = blockIdx.x, tid = threadIdx.x;
  __shared__ float e0[19 * 19];
  __shared__ float e1[19 * 19];
  int TT = T * T;
  for (int l = tid; l < TT; l += 256) {
    int t = l / T, m = l % T;
    float acc = 0.f;
    const float* lp = lhs + ((size_t)b * T + t) * NN;
    const float* rp = rhs + (size_t)b * NN * T + m;
    for (int n = 0; n < NN; n++) acc += lp[n] * rp[(size_t)n * T];
    e0[l] = sigf(acc + be[l]);
  }
  __syncthreads();
  for (int l = tid; l < TT; l += 256) {
    int t = l / T, m = l % T;
    float acc = 0.f;
    for (int j = 0; j < T; j++) acc += ve[t * T + j] * e0[j * T + m];
    e1[l] = acc;
  }
  __syncthreads();
  if (tid < T) {
    int m = tid;
    float mx = -1e30f;
    for (int t = 0; t < T; t++) mx = fmaxf(mx, e1[t * T + m]);
    float s = 0.f;
    for (int t = 0; t < T; t++) s += __expf(e1[t * T + m] - mx);
    float inv = 1.f / s;
    for (int t = 0; t < T; t++)
      e[((size_t)b * T + t) * T + m] = __expf(e1[t * T + m] - mx) * inv;
  }
}
// xt[b,f,n,t] = sum_j e[b,t,j] * h[b,f,n,j]
__global__ void k_xtat(const float* e, const float* h, float* xt, int T) {
  int total = NB * NF * NN * T;
  int idx = blockIdx.x * 256 + threadIdx.x;
  if (idx >= total) return;
  int t = idx % T;
  int n = (idx / T) % NN;
  int f = (idx / (T * NN)) % NF;
  int b = idx / (T * NN * NF);
  const float* hp = h + ((size_t)(b * NF + f) * NN + n) * T;
  float acc = 0.f;
  for (int j = 0; j < T; j++) acc += e[(b * T + t) * T + j] * hp[j];
  xt[idx] = acc;
}

// ---- spatial attention ----
__global__ void k_sa_lhs1(const float* xt, const float* w1, float* out, int T) {
  int total = NB * NN * NF;
  int idx = blockIdx.x * 256 + threadIdx.x;
  if (idx >= total) return;
  int f = idx % NF;
  int n = (idx / NF) % NN;
  int b = idx / (NF * NN);
  const float* xp = xt + ((size_t)(b * NF + f) * NN + n) * T;
  float acc = 0.f;
  for (int t = 0; t < T; t++) acc += xp[t] * w1[t];
  out[(b * NN + n) * NF + f] = acc;
}
__global__ void k_sa_lhs(const float* l1, const float* w2, float* out, int T) {
  int total = NB * NN * T;
  int idx = blockIdx.x * 256 + threadIdx.x;
  if (idx >= total) return;
  int t = idx % T;
  int n = (idx / T) % NN;
  int b = idx / (T * NN);
  float acc = 0.f;
  for (int f = 0; f < NF; f++) acc += l1[(b * NN + n) * NF + f] * w2[f * T + t];
  out[idx] = acc;  // (b,n,t)
}
__global__ void k_sa_rhs(const float* xt, const float* w3, float* out, int T) {
  int total = NB * T * NN;
  int idx = blockIdx.x * 256 + threadIdx.x;
  if (idx >= total) return;
  int n = idx % NN;
  int t = (idx / NN) % T;
  int b = idx / (NN * T);
  float acc = 0.f;
  for (int f = 0; f < NF; f++) acc += w3[f] * xt[((size_t)(b * NF + f) * NN + n) * T + t];
  out[idx] = acc;  // (b,t,n)
}
__global__ void k_sa_prod(const float* lhs, const float* rhs, const float* bs, float* s0, int T) {
  int total = NB * NN * NN;
  int idx = blockIdx.x * 256 + threadIdx.x;
  if (idx >= total) return;
  int m = idx % NN;
  int n = (idx / NN) % NN;
  int b = idx / (NN * NN);
  float acc = 0.f;
  for (int t = 0; t < T; t++)
    acc += lhs[((size_t)b * NN + n) * T + t] * rhs[((size_t)b * T + t) * NN + m];
  s0[idx] = sigf(acc + bs[(size_t)n * NN + m]);
}

// 500x500 transpose (for vs)
__global__ __launch_bounds__(256) void k_transpose(const float* in, float* outT) {
  __shared__ float tile[32][33];
  int x0 = blockIdx.x * 32, y0 = blockIdx.y * 32;
  int tx = threadIdx.x & 31, ty8 = threadIdx.x >> 5;
  for (int yy = ty8; yy < 32; yy += 8) {
    int x = x0 + tx, y = y0 + yy;
    tile[yy][tx] = (x < NN && y < NN) ? in[(size_t)y * NN + x] : 0.f;
  }
  __syncthreads();
  for (int yy = ty8; yy < 32; yy += 8) {
    int x = y0 + tx, y = x0 + yy;
    if (x < NN && y < NN) outT[(size_t)y * NN + x] = tile[tx][yy];
  }
}

// s1T[b,c,r] = (vs @ s0[b])[r,c] — 64x128 tile, double-buffered, float4 everywhere
__global__ __launch_bounds__(256) void k_gemm_vs(const float* __restrict__ vsT,
                                                 const float* __restrict__ s0,
                                                 float* __restrict__ s1t) {
  const int b = blockIdx.z;
  const int row0 = blockIdx.y * 64, col0 = blockIdx.x * 128;
  const int tid = threadIdx.x;
  const int tx = tid & 15, ty = tid >> 4;
  __shared__ float smem[6400];      // 2 x (As 16x68 + Bs 16x132)
  float acc[4][8] = {};
  const float* S0 = s0 + (size_t)b * NN * NN;
  const int nch = (NN + 15) / 16;
  float4 pa, pb0, pb1;
  auto loadregs = [&](int k0) {
    {
      int rq = tid & 15, kk = tid >> 4;
      int gk = k0 + kk, gi = row0 + rq * 4;
      float4 v = {0.f, 0.f, 0.f, 0.f};
      if (gk < NN && gi < NN) v = *(const float4*)&vsT[(size_t)gk * NN + gi];
      pa = v;
    }
#pragma unroll
    for (int it = 0; it < 2; it++) {
      int l = tid + it * 256;
      int q = l & 31, kk = l >> 5;
      int gk = k0 + kk, gc = col0 + q * 4;
      float4 v = {0.f, 0.f, 0.f, 0.f};
      if (gk < NN && gc < NN) v = *(const float4*)&S0[(size_t)gk * NN + gc];
      if (it == 0) pb0 = v; else pb1 = v;
    }
  };
  auto writebuf = [&](int buf) {
    float* As = smem + buf * 3200;
    float* Bs = As + 1088;
    {
      int rq = tid & 15, kk = tid >> 4;
      *(float4*)&As[kk * 68 + rq * 4] = pa;
    }
#pragma unroll
    for (int it = 0; it < 2; it++) {
      int l = tid + it * 256;
      int q = l & 31, kk = l >> 5;
      *(float4*)&Bs[kk * 132 + q * 4] = (it == 0) ? pb0 : pb1;
    }
  };
  loadregs(0);
  writebuf(0);
  for (int ch = 0; ch < nch; ch++) {
    int cur = ch & 1;
    if (ch + 1 < nch) loadregs((ch + 1) * 16);
    __syncthreads();
    const float* As = smem + cur * 3200;
    const float* Bs = As + 1088;
#pragma unroll
    for (int kk = 0; kk < 16; kk++) {
      float4 a4 = *(const float4*)&As[kk * 68 + ty * 4];
      float4 b0 = *(const float4*)&Bs[kk * 132 + tx * 4];
      float4 b1 = *(const float4*)&Bs[kk * 132 + 64 + tx * 4];
      float a[4] = {a4.x, a4.y, a4.z, a4.w};
      float bb[8] = {b0.x, b0.y, b0.z, b0.w, b1.x, b1.y, b1.z, b1.w};
#pragma unroll
      for (int i = 0; i < 4; i++)
#pragma unroll
        for (int j = 0; j < 8; j++) acc[i][j] += a[i] * bb[j];
    }
    if (ch + 1 < nch) writebuf((ch + 1) & 1);
  }
  float* S1 = s1t + (size_t)b * NN * NN;
  int gi0 = row0 + ty * 4;
  if (gi0 < NN) {  // NN%4==0 so gi0<NN implies gi0+3<NN
#pragma unroll
    for (int j = 0; j < 8; j++) {
      int gc = col0 + (j < 4 ? tx * 4 + j : 64 + tx * 4 + (j - 4));
      if (gc < NN) {
        float4 v = {acc[0][j], acc[1][j], acc[2][j], acc[3][j]};
        *(float4*)&S1[(size_t)gc * NN + gi0] = v;
      }
    }
  }
}

// chebT[k,n,m] = cheb[k,m,n]
__global__ void k_chebT(const float* cheb, float* ct) {
  int total = 3 * NN * NN;
  int idx = blockIdx.x * 256 + threadIdx.x;
  if (idx >= total) return;
  int m = idx % NN;
  int n = (idx / NN) % NN;
  int k = idx / (NN * NN);
  ct[idx] = cheb[((size_t)k * NN + m) * NN + n];
}

// ==== NEW cheb path: bf16x3 MFMA GEMM with theta pre-applied ====
// softmax fused with A = ct (x) s construction; emits bf16 hi/lo planes A[bc][n][m'],
// m' = (k-1)*500 + m, K padded to 1024. Also extracts sd[b][n] = s[b,n,n].
__global__ __launch_bounds__(256) void k_smax_A(const float* __restrict__ s1t,
                                                const float* __restrict__ ct, int b0,
                                                unsigned short* __restrict__ Ab,
                                                float* __restrict__ sd) {
  const int n = blockIdx.x;
  const int bc = blockIdx.y;
  const int b = b0 + bc;
  const int tid = threadIdx.x;
  const float* S = s1t + ((size_t)b * NN + n) * NN;
  __shared__ float red[256];
  float mx = -1e30f;
  for (int i = tid; i < NN; i += 256) mx = fmaxf(mx, S[i]);
  red[tid] = mx;
  __syncthreads();
  for (int s = 128; s > 0; s >>= 1) {
    if (tid < s) red[tid] = fmaxf(red[tid], red[tid + s]);
    __syncthreads();
  }
  mx = red[0];
  __syncthreads();
  float sum = 0.f;
  for (int i = tid; i < NN; i += 256) sum += __expf(S[i] - mx);
  red[tid] = sum;
  __syncthreads();
  for (int s = 128; s > 0; s >>= 1) {
    if (tid < s) red[tid] += red[tid + s];
    __syncthreads();
  }
  float inv = 1.f / red[0];
  unsigned short* Ahi = Ab + (size_t)bc * 2 * (512 * 1024) + (size_t)n * 1024;
  unsigned short* Alo = Ahi + 512 * 1024;
  const float* c1 = ct + (size_t)1 * NN * NN + (size_t)n * NN;
  const float* c2 = ct + (size_t)2 * NN * NN + (size_t)n * NN;
  for (int m = tid; m < NN; m += 256) {
    float v = __expf(S[m] - mx) * inv;
    if (m == n) sd[(size_t)b * NN + n] = v;
    float a1 = c1[m] * v, a2 = c2[m] * v;
    unsigned short h1 = bf16rne(a1);
    Ahi[m] = h1;
    Alo[m] = bf16rne(a1 - bfval(h1));
    unsigned short h2 = bf16rne(a2);
    Ahi[500 + m] = h2;
    Alo[500 + m] = bf16rne(a2 - bfval(h2));
  }
  if (tid < 24) { Ahi[1000 + tid] = 0; Alo[1000 + tid] = 0; }
}

// Y_k = h . theta_k (k=0,1,2). Y1/Y2 -> bf16 hi/lo planes B[bc][c][m'] (c = t*32+f2,
// m' = (k-1)*500+m); Y0 -> fp32 [b][c][m] (diag term for epilogue).
__global__ __launch_bounds__(256) void k_prepY(const float* __restrict__ h,
                                               const float* __restrict__ theta, int T, int b0,
                                               unsigned short* __restrict__ Bb,
                                               float* __restrict__ Y0) {
  const int t = blockIdx.x, bc = blockIdx.y, b = b0 + bc;
  const int tid = threadIdx.x;
  __shared__ float hs[NF * NN];  // [f][m]
  for (int l = tid; l < NF * NN; l += 256) {
    int m = l % NN, f = l / NN;
    hs[l] = h[((size_t)(b * NF + f) * NN + m) * T + t];
  }
  __syncthreads();
  const int lane = tid & 63, w = tid >> 6;
  for (int f2 = w; f2 < NF; f2 += 4) {
    const int c = t * NF + f2;
    unsigned short* Bhi = Bb + (size_t)bc * 2 * (640 * 1024) + (size_t)c * 1024;
    unsigned short* Blo = Bhi + 640 * 1024;
    float* Yr = Y0 + ((size_t)b * 608 + c) * NN;
    for (int m = lane; m < NN; m += 64) {
      float a0 = 0.f, a1 = 0.f, a2 = 0.f;
#pragma unroll
      for (int f = 0; f < NF; f++) {
        float hv = hs[f * NN + m];
        a0 += hv * theta[f * NF + f2];
        a1 += hv * theta[(NF + f) * NF + f2];
        a2 += hv * theta[(2 * NF + f) * NF + f2];
      }
      Yr[m] = a0;
      unsigned short h1 = bf16rne(a1);
      Bhi[m] = h1;
      Blo[m] = bf16rne(a1 - bfval(h1));
      unsigned short h2 = bf16rne(a2);
      Bhi[500 + m] = h2;
      Blo[500 + m] = bf16rne(a2 - bfval(h2));
    }
    if (lane < 24) { Bhi[1000 + lane] = 0; Blo[1000 + lane] = 0; }
  }
}

// zero pad regions: A rows [500,512) ; B rows [NFT, NB128)
__global__ void k_pad(unsigned short* Ab, unsigned short* Bb, int G, int NFT, int NB128) {
  int padB = (NB128 - NFT) * 1024;
  int totA = G * 2 * 12 * 1024;
  long long tot = totA + (long long)G * 2 * padB;
  long long i = (long long)blockIdx.x * 256 + threadIdx.x;
  if (i >= tot) return;
  if (i < totA) {
    int slot = (int)(i / (12 * 1024)), r = (int)(i % (12 * 1024));
    Ab[(size_t)slot * (512 * 1024) + 500 * 1024 + r] = 0;
  } else {
    long long j = i - totA;
    int slot = (int)(j / padB), r = (int)(j % padB);
    Bb[(size_t)slot * (640 * 1024) + (size_t)NFT * 1024 + r] = 0;
  }
}

// C[n,c] = sum_m' A[n,m'] * B[m',c] via mfma_f32_16x16x32_bf16, bf16x3 (hi/lo split).
// 128x128 tile, 4 waves (2x2, 64x64 each), BK=32, double-buffered LDS, reg-staged with
// XOR-swizzled LDS layout (write side swizzled, read side matching).
// Epilogue: out = relu(C + sd[n]*Y0[c][n]) written t-major into outX[b][n][NFT].
__global__ __launch_bounds__(256) void k_cheb_mfma(
    const unsigned short* __restrict__ Ab, const unsigned short* __restrict__ Bb,
    const float* __restrict__ Y0, const float* __restrict__ sd,
    int b0, int NFT, float* __restrict__ outX) {
  const int bc = blockIdx.z, b = b0 + bc;
  const int n0 = blockIdx.y * 128;
  const int c0 = blockIdx.x * 128;
  const int tid = threadIdx.x;
  const int lane = tid & 63;
  const int wm = (tid >> 7) & 1, wn = (tid >> 6) & 1;
  __shared__ char lds[65536];  // 2 x 32KB: Ahi 8K | Alo 8K | Bhi 8K | Blo 8K
  const unsigned short* Ahi = Ab + (size_t)bc * 2 * (512 * 1024);
  const unsigned short* Bhi = Bb + (size_t)bc * 2 * (640 * 1024);
  const unsigned short* gb[8];
  int lo_[8];
#pragma unroll
  for (int it = 0; it < 8; it++) {
    int o = it * 4096 + tid * 16;
    int p = o >> 13, q = o & 8191, r = q >> 6, sl = (q >> 4) & 3;
    const unsigned short* pb;
    if (p == 0) pb = Ahi + (size_t)(n0 + r) * 1024;
    else if (p == 1) pb = Ahi + 512 * 1024 + (size_t)(n0 + r) * 1024;
    else if (p == 2) pb = Bhi + (size_t)(c0 + r) * 1024;
    else pb = Bhi + 640 * 1024 + (size_t)(c0 + r) * 1024;
    gb[it] = pb + sl * 8;
    lo_[it] = p * 8192 + r * 64 + ((sl ^ (r & 3)) << 4);
  }
  const int off16 = ((lane >> 4) ^ (lane & 3)) << 4;
  int rA[4], rB[4];
#pragma unroll
  for (int m = 0; m < 4; m++) rA[m] = (wm * 64 + m * 16 + (lane & 15)) * 64 + off16;
#pragma unroll
  for (int j = 0; j < 4; j++) rB[j] = (wn * 64 + j * 16 + (lane & 15)) * 64 + off16 + 16384;
  f32x4 acc[4][4] = {};
  float4 st[8];
#pragma unroll
  for (int it = 0; it < 8; it++) st[it] = *(const float4*)(gb[it]);
#pragma unroll
  for (int it = 0; it < 8; it++) *(float4*)(lds + lo_[it]) = st[it];
  __syncthreads();
  for (int kc = 0; kc < 32; kc++) {
    const int cur = (kc & 1) << 15;
    if (kc < 31) {
#pragma unroll
      for (int it = 0; it < 8; it++) st[it] = *(const float4*)(gb[it] + (kc + 1) * 32);
    }
    bf16x8 ah[4], al[4], bh[4], bl[4];
#pragma unroll
    for (int m = 0; m < 4; m++) {
      ah[m] = *(const bf16x8*)(lds + cur + rA[m]);
      al[m] = *(const bf16x8*)(lds + cur + rA[m] + 8192);
    }
#pragma unroll
    for (int j = 0; j < 4; j++) {
      bh[j] = *(const bf16x8*)(lds + cur + rB[j]);
      bl[j] = *(const bf16x8*)(lds + cur + rB[j] + 8192);
    }
#pragma unroll
    for (int m = 0; m < 4; m++)
#pragma unroll
      for (int j = 0; j < 4; j++) {
        acc[m][j] = __builtin_amdgcn_mfma_f32_16x16x32_bf16(ah[m], bh[j], acc[m][j], 0, 0, 0);
        acc[m][j] = __builtin_amdgcn_mfma_f32_16x16x32_bf16(al[m], bh[j], acc[m][j], 0, 0, 0);
        acc[m][j] = __builtin_amdgcn_mfma_f32_16x16x32_bf16(ah[m], bl[j], acc[m][j], 0, 0, 0);
      }
    if (kc < 31) {
      const int nxt = cur ^ 32768;
#pragma unroll
      for (int it = 0; it < 8; it++) *(float4*)(lds + nxt + lo_[it]) = st[it];
    }
    __syncthreads();
  }
#pragma unroll
  for (int m = 0; m < 4; m++) {
    const int nb = n0 + wm * 64 + m * 16 + (lane >> 4) * 4;
#pragma unroll
    for (int j = 0; j < 4; j++) {
      const int c = c0 + wn * 64 + j * 16 + (lane & 15);
      if (c < NFT) {
        const float* Yc = Y0 + ((size_t)b * 608 + c) * NN;
#pragma unroll
        for (int rg = 0; rg < 4; rg++) {
          const int n = nb + rg;
          if (n < NN) {
            float v = acc[m][j][rg] + sd[(size_t)b * NN + n] * Yc[n];
            outX[((size_t)b * NN + n) * NFT + c] = fmaxf(v, 0.f);
          }
        }
      }
    }
  }
}

// ---- layer norm over (C,N,T) per sample; one block per b ----
__global__ __launch_bounds__(256) void k_ln_stat(const float* x, float* stat, int M) {
  int b = blockIdx.x;
  const float* xp = x + (size_t)b * M;
  float s1 = 0.f, s2 = 0.f;
  for (int i = threadIdx.x; i < M; i += 256) {
    float v = xp[i]; s1 += v; s2 += v * v;
  }
  __shared__ float r1[256], r2[256];
  int tid = threadIdx.x;
  r1[tid] = s1; r2[tid] = s2;
  __syncthreads();
  for (int s = 128; s > 0; s >>= 1) {
    if (tid < s) { r1[tid] += r1[tid + s]; r2[tid] += r2[tid + s]; }
    __syncthreads();
  }
  if (tid == 0) {
    float mean = r1[0] / M;
    float var = r2[0] / M - mean * mean;
    stat[b * 2] = mean;
    stat[b * 2 + 1] = rsqrtf(var + 1e-5f);
  }
}
__global__ void k_ln_norm(const float* x, const float* stat, const float* wn, const float* bn,
                          float* out, int M) {
  int total = NB * M;
  int idx = blockIdx.x * 256 + threadIdx.x;
  if (idx >= total) return;
  int b = idx / M;
  int i = idx % M;
  float y = (x[idx] - stat[b * 2]) * stat[b * 2 + 1];
  out[idx] = y * wn[i] + bn[i];
}

// ---- final head ----
__global__ void k_fin1(const float* h, const float* w, const float* bias, const float* skip,
                       float* out) {
  int total = NB * 64 * NN;
  int idx = blockIdx.x * 256 + threadIdx.x;
  if (idx >= total) return;
  int n = idx % NN;
  int c = (idx / NN) % 64;
  int b = idx / (NN * 64);
  float v = bias[c];
  for (int ci = 0; ci < 32; ci++) v += w[c * 32 + ci] * h[(b * NF + ci) * NN + n];
  v += skip[((size_t)(b * 64 + c) * NN + n) * 7 + 6];
  out[idx] = fmaxf(v, 0.f);
}
__global__ void k_fin2(const float* in, const float* w, const float* bias, float* out) {
  int total = NB * 128 * NN;
  int idx = blockIdx.x * 256 + threadIdx.x;
  if (idx >= total) return;
  int n = idx % NN;
  int c = (idx / NN) % 128;
  int b = idx / (NN * 128);
  float v = bias[c];
  for (int ci = 0; ci < 64; ci++) v += w[c * 64 + ci] * in[(b * 64 + ci) * NN + n];
  out[idx] = fmaxf(v, 0.f);
}
__global__ void k_fin3(const float* in, const float* w, const float* bias, float* out) {
  int total = NB * 12 * NN;
  int idx = blockIdx.x * 256 + threadIdx.x;
  if (idx >= total) return;
  int n = idx % NN;
  int c = (idx / NN) % 12;
  int b = idx / (NN * 12);
  float v = bias[c];
  for (int ci = 0; ci < 128; ci++) v += w[c * 128 + ci] * in[(b * 128 + ci) * NN + n];
  out[idx] = v;
}

#define G1(tot) dim3((unsigned)(((tot) + 255) / 256)), dim3(256), 0, stream

extern "C" void kernel_launch(void* const* d_in, const int* in_sizes, int n_in,
                              void* d_out, int out_size, void* d_ws, size_t ws_size,
                              hipStream_t stream) {
  (void)in_sizes; (void)n_in; (void)out_size;
  auto I = [&](int i) { return (const float*)d_in[i]; };
  float* W = (float*)d_ws;
  size_t off = 0;
  auto alloc = [&](size_t nel) { float* p = W + off; off += nel; return p; };

  float* bufA  = alloc(9728000);   // h / residual [B,32,N,19max]
  float* bufB  = alloc(9728000);   // h after fc1; later cheb output (t-major, in place)
  float* bufC  = alloc(9728000);   // x_tat -> s1T
  float* bufSK = alloc(7168000);   // skip [B,64,N,7]
  float* skip0 = alloc(1024000);   // skip [B,64,N,1]
  float* P1    = alloc(9728000);   // s0 ; then Y0 [b][608][500] ; reused for F1/F2 at end
  float* CT    = alloc(750000);    // chebT
  float* VST   = alloc(250000);    // vs transposed (per layer)
  float* TL1   = alloc(19456);
  float* TLH   = alloc(304000);
  float* TRH   = alloc(304000);
  float* TE    = alloc(11552);
  float* SL1   = alloc(512000);
  float* SLH   = alloc(304000);
  float* SRH   = alloc(304000);
  float* ACC   = alloc(64);
  float* SD    = alloc(16000);     // sd[b][n] = s[b,n,n]
  // batch group size for bf16 A/B staging buffers, chosen to fit the workspace
  size_t fixedOff = off;
  int G = 32;
  while (G > 1 && ws_size != 0 && (fixedOff + (size_t)G * 1179648) * 4 > ws_size) G >>= 1;
  float* BbF = alloc((size_t)G * 655360);  // B planes: [bc][2][640][1024] bf16
  float* AbF = alloc((size_t)G * 524288);  // A planes: [bc][2][512][1024] bf16
  unsigned short* Bb = (unsigned short*)BbF;
  unsigned short* Ab = (unsigned short*)AbF;
  float* P2 = bufC;                // s1T lives in bufC until smax_A consumes it
  float* F1 = P1;                  // [B,64,N] final head, after P1 (Y0) is dead
  float* F2 = P1 + 1024000;        // [B,128,N]

  k_start<<<G1(NB * NF * NN * 19)>>>(I(0), I(1), I(2), bufA);
  k_skip0<<<G1(NB * 64 * NN)>>>(I(0), I(3), I(4), skip0);
  k_chebT<<<G1(3 * NN * NN)>>>(I(59), CT);

  dim3 ggt((NN + 7) / 8, NB), bgt(256);
  auto gtufc = [&](int Ti, int To, const float* hin, const float* fw, const float* fb,
                   const float* res, float* o) {
    if (Ti == 19 && To == 19)
      k_gtufc_t<19, 19><<<ggt, bgt, 0, stream>>>(hin, I(5), I(6), I(7), I(8), I(9), I(10), fw, fb, res, o);
    else if (Ti == 13 && To == 13)
      k_gtufc_t<13, 13><<<ggt, bgt, 0, stream>>>(hin, I(5), I(6), I(7), I(8), I(9), I(10), fw, fb, res, o);
    else
      k_gtufc_t<7, 7><<<ggt, bgt, 0, stream>>>(hin, I(5), I(6), I(7), I(8), I(9), I(10), fw, fb, res, o);
  };
  auto gtufcx = [&](int Ti, int To, const float* hin, const float* fw, const float* fb,
                    const float* res, float* o) {
    if (Ti == 19)
      k_gtufc_x<19, 13><<<ggt, bgt, 0, stream>>>(hin, I(5), I(6), I(7), I(8), I(9), I(10), fw, fb, res, o);
    else if (Ti == 13)
      k_gtufc_x<13, 7><<<ggt, bgt, 0, stream>>>(hin, I(5), I(6), I(7), I(8), I(9), I(10), fw, fb, res, o);
    else
      k_gtufc_x<7, 1><<<ggt, bgt, 0, stream>>>(hin, I(5), I(6), I(7), I(8), I(9), I(10), fw, fb, res, o);
  };

  const int Tin[3] = {19, 13, 7}, Tout[3] = {13, 7, 1};
  for (int i = 0; i < 3; i++) {
    int Ti = Tin[i], To = Tout[i];
    // gated TCN + fc1 + relu-add : bufA -> bufB
    gtufc(Ti, Ti, bufA, I(11 + 2 * i), I(12 + 2 * i), nullptr, bufB);
    // skip conv
    if (i == 0)
      k_skipconv_t<19, 13><<<ggt, bgt, 0, stream>>>(bufB, I(23), I(24), skip0, 1, bufSK);
    else if (i == 1)
      k_skipconv_t<13, 7><<<ggt, bgt, 0, stream>>>(bufB, I(25), I(26), bufSK, 7, bufSK);
    else
      k_skipconv_t<7, 1><<<ggt, bgt, 0, stream>>>(bufB, I(27), I(28), bufSK, 7, bufSK);
    // temporal attention
    int ba = 29 + i * 10;
    k_ta_lhs1<<<G1(NB * Ti * NF)>>>(bufB, I(ba + 0), TL1, Ti);
    k_ta_lhs<<<G1(NB * Ti * NN)>>>(TL1, I(ba + 1), TLH, Ti);
    k_ta_rhs<<<G1(NB * NN * Ti)>>>(bufB, I(ba + 2), TRH, Ti);
    k_ta_att<<<dim3(NB), dim3(256), 0, stream>>>(TLH, TRH, I(ba + 3), I(ba + 4), TE, Ti);
    k_xtat<<<G1(NB * NF * NN * Ti)>>>(TE, bufB, bufC, Ti);  // x_tat into bufC
    // spatial attention
    k_sa_lhs1<<<G1(NB * NN * NF)>>>(bufC, I(ba + 5), SL1, Ti);
    k_sa_lhs<<<G1(NB * NN * Ti)>>>(SL1, I(ba + 6), SLH, Ti);
    k_sa_rhs<<<G1(NB * Ti * NN)>>>(bufC, I(ba + 7), SRH, Ti);
    k_sa_prod<<<G1(NB * NN * NN)>>>(SLH, SRH, I(ba + 8), P1, Ti);  // x_tat consumed
    k_transpose<<<dim3(16, 16), dim3(256), 0, stream>>>(I(ba + 9), VST);
    {
      dim3 gg((NN + 127) / 128, 8, NB);
      k_gemm_vs<<<gg, dim3(256), 0, stream>>>(VST, P1, P2);  // s1T into bufC; P1 free
    }
    // ==== cheb conv via bf16x3 MFMA ====
    int NFT = NF * Ti, NB128 = (NFT + 127) & ~127;
    k_pad<<<G1(G * 2 * 12 * 1024 + G * 2 * (NB128 - NFT) * 1024)>>>(Ab, Bb, G, NFT, NB128);
    for (int b0 = 0; b0 < NB; b0 += G) {
      // Y_k = h . theta_k : bufB (h) -> Bb (bf16 hi/lo) + P1 (Y0 fp32)
      k_prepY<<<dim3(Ti, G), dim3(256), 0, stream>>>(bufB, I(60), Ti, b0, Bb, P1);
      // softmax + A = ctT (x) s -> Ab (bf16 hi/lo), sd
      k_smax_A<<<dim3(NN, G), dim3(256), 0, stream>>>(P2, CT, b0, Ab, SD);
      // GEMM + diag/relu epilogue; writes outX in place over dead h slices of bufB
      dim3 gm(NB128 / 128, 4, G);
      k_cheb_mfma<<<gm, dim3(256), 0, stream>>>(Ab, Bb, P1, SD, b0, NFT, bufB);
    }
    // second gated TCN (t-major input) + fc2 + relu-add + residual : bufB (+bufA) -> bufC
    gtufcx(Ti, To, bufB, I(17 + 2 * i), I(18 + 2 * i), bufA, bufC);
    // layer norm: bufC -> bufA
    int M = NF * NN * To;
    k_ln_stat<<<dim3(NB), dim3(256), 0, stream>>>(bufC, ACC, M);
    k_ln_norm<<<G1(NB * M)>>>(bufC, ACC, I(61 + 2 * i), I(62 + 2 * i), bufA, M);
  }
  // final head
  k_fin1<<<G1(NB * 64 * NN)>>>(bufA, I(67), I(68), bufSK, F1);
  k_fin2<<<G1(NB * 128 * NN)>>>(F1, I(69), I(70), F2);
  k_fin3<<<G1(NB * 12 * NN)>>>(F2, I(71), I(72), (float*)d_out);
}